// Round 9
// baseline (227.685 us; speedup 1.0000x reference)
//
#include <hip/hip_runtime.h>

typedef _Float16 half_t;
typedef _Float16 hx8 __attribute__((ext_vector_type(8)));
typedef _Float16 hx4 __attribute__((ext_vector_type(4)));
typedef float fx4 __attribute__((ext_vector_type(4)));

#define LOG2E 1.44269504088896f
#define TAU 0.1f
#define NSPLIT 8

// ---------------- Kernel 0: pack W1/W2 into fp16 A-fragment order ----------
// (unchanged — verified)
__global__ __launch_bounds__(256) void wpack_kernel(
    const float* __restrict__ W1, const float* __restrict__ W2,
    half_t* __restrict__ Wh1, half_t* __restrict__ Wh2)
{
  const int job = blockIdx.x*256 + threadIdx.x;   // 0..4095
  const int lane = job & 63;
  const int frag = (job >> 6) & 31;               // mt*4 + ks
  const int mat  = job >> 11;
  const int mt = frag >> 2, ks = frag & 3;
  const int q = lane >> 4, c = lane & 15;
  const float* W = mat ? W2 : W1;
  half_t* Wh = mat ? Wh2 : Wh1;
  hx8 v;
#pragma unroll
  for (int j=0;j<8;++j)
    v[j] = (half_t)W[(size_t)(ks*32 + q*8 + j)*128 + mt*16 + c];
  *(hx8*)(Wh + ((size_t)frag*64 + lane)*8) = v;
}

// ---------------- Kernel 1: fused ztrans + MLP (packed W frags) ------------
// (unchanged from round 8 — verified)
__global__ __launch_bounds__(256) void mlpz_kernel(
    const float* __restrict__ Z, const half_t* __restrict__ Wh1,
    const float* __restrict__ b1, const half_t* __restrict__ Wh2,
    const float* __restrict__ b2, half_t* __restrict__ T,
    half_t* __restrict__ Zth)
{
  __shared__ float Ztile[16*132];       // 8.45 KB
  __shared__ half_t Hs[16*136];         // 4.35 KB
  const int tid = threadIdx.x;
  const int w = tid >> 6, lane = tid & 63;
  const int q = lane >> 4, c = lane & 15;
  const int rb = blockIdx.x*16;

#pragma unroll
  for (int i=0;i<2;++i) {
    int fid = i*256 + tid;
    int r = fid >> 5, c4 = (fid & 31)*4;
    *(fx4*)(&Ztile[r*132 + c4]) = *(const fx4*)(Z + (size_t)(rb + r)*128 + c4);
  }
  __syncthreads();

  {
    const int d = tid >> 1, h = tid & 1;  // paired: 2 threads per d-row
    hx8 hv;
#pragma unroll
    for (int u=0;u<8;++u) hv[u] = (half_t)Ztile[(h*8 + u)*132 + d];
    *(hx8*)(Zth + (size_t)d*8192 + rb + h*8) = hv;
  }

  hx8 zb[4];
#pragma unroll
  for (int ks=0;ks<4;++ks) {
    fx4 a = *(const fx4*)(&Ztile[c*132 + ks*32 + q*8]);
    fx4 b = *(const fx4*)(&Ztile[c*132 + ks*32 + q*8 + 4]);
#pragma unroll
    for (int u=0;u<4;++u) { zb[ks][u] = (half_t)a[u]; zb[ks][4+u] = (half_t)b[u]; }
  }

  // ---- layer 1: wave w owns mt = 2w, 2w+1 ----
#pragma unroll
  for (int m2=0;m2<2;++m2) {
    const int mt = w*2 + m2;
    fx4 acc = (fx4){0.f,0.f,0.f,0.f};
#pragma unroll
    for (int ks=0;ks<4;++ks) {
      hx8 aw = *(const hx8*)(Wh1 + ((size_t)(mt*4 + ks)*64 + lane)*8);
      acc = __builtin_amdgcn_mfma_f32_16x16x32_f16(aw, zb[ks], acc, 0,0,0);
    }
    fx4 bias = *(const fx4*)(b1 + mt*16 + 4*q);
    hx4 hv;
#pragma unroll
    for (int i=0;i<4;++i) {
      float h = acc[i] + bias[i];
      hv[i] = (half_t)(h > 0.f ? h : 0.f);
    }
    *(hx4*)(&Hs[c*136 + mt*16 + 4*q]) = hv;
  }
  __syncthreads();

  // ---- layer 2 ----
  hx8 hb[4];
#pragma unroll
  for (int ks=0;ks<4;++ks) hb[ks] = *(const hx8*)(&Hs[c*136 + ks*32 + q*8]);
#pragma unroll
  for (int m2=0;m2<2;++m2) {
    const int mt = w*2 + m2;
    fx4 acc = (fx4){0.f,0.f,0.f,0.f};
#pragma unroll
    for (int ks=0;ks<4;++ks) {
      hx8 aw = *(const hx8*)(Wh2 + ((size_t)(mt*4 + ks)*64 + lane)*8);
      acc = __builtin_amdgcn_mfma_f32_16x16x32_f16(aw, hb[ks], acc, 0,0,0);
    }
    fx4 bias = *(const fx4*)(b2 + mt*16 + 4*q);
    hx4 tv;
#pragma unroll
    for (int i=0;i<4;++i) tv[i] = (half_t)(acc[i] + bias[i]);
    *(hx4*)(T + (size_t)(rb + c)*128 + mt*16 + 4*q) = tv;
  }
}

// ---------------- Kernel 2: flash attention partials (v9: occupancy done right)
// R8 post-mortem: 1-barrier + full-iter prefetch NEUTRAL -> the pacer is the
// per-wave serial chain at 2 waves/SIMD, with the LDS pipe (~40% busy) on it.
// v9 mechanism: nt=1 @ 64-key tiles + az (PV A-operand) DIRECT FROM GLOBAL.
// Op accounting vs R6 (why this dodges R3's trap): ak LDS reads double but
// az LDS reads vanish and P ops halve -> chip-wide LDS ops EQUAL; wave count
// doubles (grid 1024 = 128 qb x 8 kh); per-wave softmax chain halves; Zt
// slice per kh = 256 KB = per-XCD-L2-resident. vmcnt FIFO discipline (R1
// lesson): az issued FIRST, DMA (T only) second, order pinned with
// sched_barrier(0) -> PV waits vmcnt(4), prefetch stays in flight.
// LDS 40 KB (Tbuf 32 dbuf + Pbuf 8 private). VGPR est ~150 -> 3 waves/SIMD
// = 12 waves/CU (was 8).
// Lessons ledger: (1) >=64-key tiles (R2); (2) occupancy via LESS REUSE is
// a loss (R3) — this trades LDS ops for L2 BW instead; (3) az-after-DMA
// drains prefetch (R1); (4) T13 defer-max HURT (R4); (5) deferred l-sum WIN
// (R6); (6) v_pk_f32 on live accs -> spill cliff (R7); (7) P^T rows 128B,
// sw=(c&7)*8; (8) NEVER __launch_bounds__(256,3+); (9) barrier count is
// NOT the cost (R8).
__global__ __launch_bounds__(256,2) void flash_kernel(
    const half_t* __restrict__ T, const half_t* __restrict__ Zt,
    half_t* __restrict__ Pacc, float* __restrict__ Pm, float* __restrict__ Pl)
{
  __shared__ half_t Tbuf[2][16*512];    // 32 KB (64 keys x 128 d, dbuf)
  __shared__ half_t Pbuf[4][16*64];     // 8 KB — per-wave private P^T
  const int tid = threadIdx.x;
  const int w = tid >> 6, lane = tid & 63;
  const int q = lane >> 4, c = lane & 15;
  const int bx = blockIdx.x;
  const int qb = bx >> 3, kh = bx & 7;  // 128 q-blocks (64 rows) x 8 splits
  const int wrow = qb*64 + w*16;        // this wave's 16 q-rows
  const int sw = (c & 7) * 8;

  hx8 bq[4];
#pragma unroll
  for (int ks=0;ks<4;++ks)
    bq[ks] = *(const hx8*)(T + (size_t)(wrow + c)*128 + ks*32 + q*8);

  fx4 oacc[8];
#pragma unroll
  for (int mtd=0;mtd<8;++mtd) oacc[mtd] = (fx4){0.f,0.f,0.f,0.f};
  float m_run = -1e30f;
  float l_run = 0.f;                    // per-lane partial (reduced at end)

  const int kbase = kh*1024;
  half_t* Psw = &Pbuf[w][0];            // wave-private 16x64-half P^T

  auto issue_loads = [&](int kt0, int b) {
    // T fills only now: 16 frags / 4 waves = 4 each
#pragma unroll
    for (int i=0;i<4;++i) {
      int f = w*4 + i, mt = f >> 2, ks = f & 3;
      const half_t* gp = T + (size_t)(kt0 + mt*16 + c)*128 + ks*32 + q*8;
      half_t* lp = &Tbuf[b][f*512 + lane*8];
      __builtin_amdgcn_global_load_lds(
          (const __attribute__((address_space(1))) void*)gp,
          (__attribute__((address_space(3))) void*)lp, 16, 0, 0);
    }
  };

  issue_loads(kbase, 0);

  for (int t=0;t<16;++t) {
    const int cur = t & 1;
    __syncthreads();                    // drains DMA of cur + publishes

    // ---- az loads FIRST (oldest in vmcnt FIFO; consumed by PV below) ----
    const half_t* zbase = Zt + (size_t)c*8192 + kbase + t*64 + q*8;
    hx8 az[8][2];
#pragma unroll
    for (int mtd=0;mtd<8;++mtd)
#pragma unroll
      for (int ks2=0;ks2<2;++ks2)
        az[mtd][ks2] = *(const hx8*)(zbase + (size_t)mtd*16*8192 + ks2*32);
    __builtin_amdgcn_sched_barrier(0);  // pin: az issued before DMA

    // ---- prefetch t+1 (younger than az -> PV waits leave these in flight)
    if (t < 15) issue_loads(kbase + (t+1)*64, cur ^ 1);
    __builtin_amdgcn_sched_barrier(0);  // pin: DMA issued before compute

    half_t* Tcur = Tbuf[cur];

    // ---- scores (64 keys x 16 q-rows) ----
    fx4 sacc[4];
#pragma unroll
    for (int mt=0;mt<4;++mt) sacc[mt] = (fx4){0.f,0.f,0.f,0.f};
#pragma unroll
    for (int ks=0;ks<4;++ks)
#pragma unroll
      for (int mt=0;mt<4;++mt) {
        hx8 ak = *(const hx8*)(&Tcur[(mt*4+ks)*512 + lane*8]);
        sacc[mt] = __builtin_amdgcn_mfma_f32_16x16x32_f16(ak, bq[ks], sacc[mt], 0,0,0);
      }

    // ---- online softmax (single chain; deferred l-sum; max3 tree) ----
    {
      float a0 = fmaxf(fmaxf(sacc[0][0], sacc[0][1]), sacc[0][2]);
      float a1 = fmaxf(fmaxf(sacc[0][3], sacc[1][0]), sacc[1][1]);
      float a2 = fmaxf(fmaxf(sacc[1][2], sacc[1][3]), sacc[2][0]);
      float a3 = fmaxf(fmaxf(sacc[2][1], sacc[2][2]), sacc[2][3]);
      float a4 = fmaxf(fmaxf(sacc[3][0], sacc[3][1]), sacc[3][2]);
      float mx = fmaxf(fmaxf(fmaxf(a0, a1), fmaxf(a2, a3)),
                       fmaxf(a4, sacc[3][3]));
      mx = fmaxf(mx, __shfl_xor(mx, 16, 64));
      mx = fmaxf(mx, __shfl_xor(mx, 32, 64));
      float mnew = fmaxf(m_run, mx);
      float alpha = __builtin_amdgcn_exp2f((m_run - mnew)*LOG2E);
      m_run = mnew;
      float nb = mnew*LOG2E;
      float rs = 0.f;
#pragma unroll
      for (int mt=0;mt<4;++mt) {
        hx4 pkv;
#pragma unroll
        for (int i=0;i<4;++i) {
          float p = __builtin_amdgcn_exp2f(sacc[mt][i]*LOG2E - nb);
          rs += p;
          pkv[i] = (half_t)p;
        }
        // P^T into wave-private region (128B rows, conflict-free)
        *(hx4*)(&Psw[c*64 + ((mt*16 + 4*q) ^ sw)]) = pkv;
      }
      l_run = l_run*alpha + rs;
#pragma unroll
      for (int mtd=0;mtd<8;++mtd)
#pragma unroll
        for (int i=0;i<4;++i) oacc[mtd][i] *= alpha;
    }

    // ---- PV: az from registers (global-loaded), bp from private LDS ----
#pragma unroll
    for (int ks2=0;ks2<2;++ks2) {
      hx8 bp = *(const hx8*)(&Psw[c*64 + ((ks2*32 + q*8) ^ sw)]);
#pragma unroll
      for (int mtd=0;mtd<8;++mtd)
        oacc[mtd] = __builtin_amdgcn_mfma_f32_16x16x32_f16(az[mtd][ks2], bp, oacc[mtd], 0,0,0);
    }
  }

  // epilogue: reduce deferred l partials; map into merge's (qb128,kh,rr)
  float lf = l_run;
  lf += __shfl_xor(lf, 16, 64);
  lf += __shfl_xor(lf, 32, 64);
  float inv = 1.0f / lf;
  const size_t prow = (size_t)(((qb >> 1)*8 + kh)*128 + (qb & 1)*64 + w*16 + c);
#pragma unroll
  for (int mtd=0;mtd<8;++mtd) {
    hx4 ov;
#pragma unroll
    for (int i=0;i<4;++i) ov[i] = (half_t)(oacc[mtd][i]*inv);
    *(hx4*)(Pacc + prow*128 + mtd*16 + 4*q) = ov;
  }
  if (q == 0) {
    Pm[prow] = m_run;
    Pl[prow] = lf;
  }
}

// ---------------- Kernel 3: merge NSPLIT key-split partials ----------------
// (unchanged)
__global__ __launch_bounds__(256) void merge_kernel(
    const float* __restrict__ Z, const half_t* __restrict__ Pacc,
    const float* __restrict__ Pm, const float* __restrict__ Pl,
    float* __restrict__ out)
{
  const int th = blockIdx.x*256 + threadIdx.x;
  const int r = th >> 5, cg = th & 31;
  const int qb = r >> 7, rr = r & 127;
  float mk[NSPLIT], lk[NSPLIT];
  float M = -1e30f;
#pragma unroll
  for (int k=0;k<NSPLIT;++k) {
    int p = qb*NSPLIT + k;
    mk[k] = Pm[p*128 + rr];
    lk[k] = Pl[p*128 + rr];
    M = fmaxf(M, mk[k]);
  }
  float L = 0.f, wk[NSPLIT];
#pragma unroll
  for (int k=0;k<NSPLIT;++k) { wk[k] = lk[k]*__builtin_amdgcn_exp2f((mk[k]-M)*LOG2E); L += wk[k]; }
  float o0=0.f,o1=0.f,o2=0.f,o3=0.f;
#pragma unroll
  for (int k=0;k<NSPLIT;++k) {
    int p = qb*NSPLIT + k;
    hx4 v = *(const hx4*)(Pacc + ((size_t)p*128 + rr)*128 + cg*4);
    o0 += wk[k]*(float)v[0]; o1 += wk[k]*(float)v[1];
    o2 += wk[k]*(float)v[2]; o3 += wk[k]*(float)v[3];
  }
  float invL = 1.0f / L;
  fx4 zv = *(const fx4*)(Z + (size_t)r*128 + cg*4);
  fx4 res;
  res[0] = (1.f-TAU)*zv[0] + TAU*o0*invL;
  res[1] = (1.f-TAU)*zv[1] + TAU*o1*invL;
  res[2] = (1.f-TAU)*zv[2] + TAU*o2*invL;
  res[3] = (1.f-TAU)*zv[3] + TAU*o3*invL;
  *(fx4*)(out + (size_t)r*128 + cg*4) = res;
}

extern "C" void kernel_launch(void* const* d_in, const int* in_sizes, int n_in,
                              void* d_out, int out_size, void* d_ws, size_t ws_size,
                              hipStream_t stream) {
  const float* Z  = (const float*)d_in[0];
  const float* W1 = (const float*)d_in[1];
  const float* b1 = (const float*)d_in[2];
  const float* W2 = (const float*)d_in[3];
  const float* b2 = (const float*)d_in[4];
  float* out = (float*)d_out;

  char* ws = (char*)d_ws;
  const size_t NBLK = 64 * NSPLIT;                                // 512 groups
  half_t* Thi  = (half_t*)(ws);                                   // 2 MB
  half_t* Zth  = (half_t*)(ws + (size_t)2*1024*1024);             // 2 MB
  half_t* Pacc = (half_t*)(ws + (size_t)4*1024*1024);             // 16 MB
  float*  Pm   = (float*)(ws + (size_t)4*1024*1024 + NBLK*128*128*2);
  float*  Pl   = Pm + NBLK*128;
  half_t* Wh1  = (half_t*)(ws + (size_t)20*1024*1024 + 512*1024); // 32 KB
  half_t* Wh2  = Wh1 + 32*64*8;                                   // 32 KB

  hipLaunchKernelGGL(wpack_kernel, dim3(16),   dim3(256), 0, stream, W1, W2, Wh1, Wh2);
  hipLaunchKernelGGL(mlpz_kernel,  dim3(512),  dim3(256), 0, stream, Z, Wh1, b1, Wh2, b2, Thi, Zth);
  hipLaunchKernelGGL(flash_kernel, dim3(128*NSPLIT), dim3(256), 0, stream, Thi, Zth, Pacc, Pm, Pl);
  hipLaunchKernelGGL(merge_kernel, dim3(1024), dim3(256), 0, stream, Z, Pacc, Pm, Pl, out);
}

// Round 10
// 123.733 us; speedup vs baseline: 1.8401x; 1.8401x over previous
//
#include <hip/hip_runtime.h>

typedef _Float16 half_t;
typedef _Float16 hx8 __attribute__((ext_vector_type(8)));
typedef _Float16 hx4 __attribute__((ext_vector_type(4)));
typedef float fx4 __attribute__((ext_vector_type(4)));

#define LOG2E 1.44269504088896f
#define TAU 0.1f
#define NSPLIT 8

// ---------------- Kernel 0: pack W1/W2 into fp16 A-fragment order ----------
// (unchanged — verified)
__global__ __launch_bounds__(256) void wpack_kernel(
    const float* __restrict__ W1, const float* __restrict__ W2,
    half_t* __restrict__ Wh1, half_t* __restrict__ Wh2)
{
  const int job = blockIdx.x*256 + threadIdx.x;   // 0..4095
  const int lane = job & 63;
  const int frag = (job >> 6) & 31;               // mt*4 + ks
  const int mat  = job >> 11;
  const int mt = frag >> 2, ks = frag & 3;
  const int q = lane >> 4, c = lane & 15;
  const float* W = mat ? W2 : W1;
  half_t* Wh = mat ? Wh2 : Wh1;
  hx8 v;
#pragma unroll
  for (int j=0;j<8;++j)
    v[j] = (half_t)W[(size_t)(ks*32 + q*8 + j)*128 + mt*16 + c];
  *(hx8*)(Wh + ((size_t)frag*64 + lane)*8) = v;
}

// ---------------- Kernel 1: fused ztrans + MLP (v4: split-mh, 4 blocks/CU) -
// R9 accounting: "other" ~= 67us; merge ~3us + wpack ~1us by BW math ->
// mlpz is the prime suspect (2 blocks/CU, serial chain — same latency-bound
// shape flash had). v4: grid 1024 = 512 row-tiles x 2 output-halves (mh).
// Each block: FULL layer-1 (32 MFMAs, duplicated chip-wide — trivial),
// HALF of layer-2 (wave w computes the single frag mt = mh*4+w), HALF of
// the Zth emission (d in [mh*64, mh*64+64)). Z staged twice chip-wide
// (+4MB reads ~ +0.6us) for 2x blocks/CU (2->4) and halved tail.
__global__ __launch_bounds__(256) void mlpz_kernel(
    const float* __restrict__ Z, const half_t* __restrict__ Wh1,
    const float* __restrict__ b1, const half_t* __restrict__ Wh2,
    const float* __restrict__ b2, half_t* __restrict__ T,
    half_t* __restrict__ Zth)
{
  __shared__ float Ztile[16*132];       // 8.45 KB
  __shared__ half_t Hs[16*136];         // 4.35 KB
  const int tid = threadIdx.x;
  const int w = tid >> 6, lane = tid & 63;
  const int q = lane >> 4, c = lane & 15;
  const int bx = blockIdx.x;
  const int rb = (bx >> 1) * 16;        // row-tile
  const int mh = bx & 1;                // output half: mt in [mh*4, mh*4+4)

#pragma unroll
  for (int i=0;i<2;++i) {
    int fid = i*256 + tid;
    int r = fid >> 5, c4 = (fid & 31)*4;
    *(fx4*)(&Ztile[r*132 + c4]) = *(const fx4*)(Z + (size_t)(rb + r)*128 + c4);
  }
  __syncthreads();

  // Zth emission: this block's 64 d-rows (paired threads share a 32B region)
  if (tid < 128) {
    const int d = mh*64 + (tid >> 1), h = tid & 1;
    hx8 hv;
#pragma unroll
    for (int u=0;u<8;++u) hv[u] = (half_t)Ztile[(h*8 + u)*132 + d];
    *(hx8*)(Zth + (size_t)d*8192 + rb + h*8) = hv;
  }

  hx8 zb[4];
#pragma unroll
  for (int ks=0;ks<4;++ks) {
    fx4 a = *(const fx4*)(&Ztile[c*132 + ks*32 + q*8]);
    fx4 b = *(const fx4*)(&Ztile[c*132 + ks*32 + q*8 + 4]);
#pragma unroll
    for (int u=0;u<4;++u) { zb[ks][u] = (half_t)a[u]; zb[ks][4+u] = (half_t)b[u]; }
  }

  // ---- layer 1 (FULL): wave w owns mt = 2w, 2w+1 ----
#pragma unroll
  for (int m2=0;m2<2;++m2) {
    const int mt = w*2 + m2;
    fx4 acc = (fx4){0.f,0.f,0.f,0.f};
#pragma unroll
    for (int ks=0;ks<4;++ks) {
      hx8 aw = *(const hx8*)(Wh1 + ((size_t)(mt*4 + ks)*64 + lane)*8);
      acc = __builtin_amdgcn_mfma_f32_16x16x32_f16(aw, zb[ks], acc, 0,0,0);
    }
    fx4 bias = *(const fx4*)(b1 + mt*16 + 4*q);
    hx4 hv;
#pragma unroll
    for (int i=0;i<4;++i) {
      float h = acc[i] + bias[i];
      hv[i] = (half_t)(h > 0.f ? h : 0.f);
    }
    *(hx4*)(&Hs[c*136 + mt*16 + 4*q]) = hv;
  }
  __syncthreads();

  // ---- layer 2 (HALF): wave w computes the single frag mt = mh*4 + w ----
  hx8 hb[4];
#pragma unroll
  for (int ks=0;ks<4;++ks) hb[ks] = *(const hx8*)(&Hs[c*136 + ks*32 + q*8]);
  {
    const int mt = mh*4 + w;
    fx4 acc = (fx4){0.f,0.f,0.f,0.f};
#pragma unroll
    for (int ks=0;ks<4;++ks) {
      hx8 aw = *(const hx8*)(Wh2 + ((size_t)(mt*4 + ks)*64 + lane)*8);
      acc = __builtin_amdgcn_mfma_f32_16x16x32_f16(aw, hb[ks], acc, 0,0,0);
    }
    fx4 bias = *(const fx4*)(b2 + mt*16 + 4*q);
    hx4 tv;
#pragma unroll
    for (int i=0;i<4;++i) tv[i] = (half_t)(acc[i] + bias[i]);
    *(hx4*)(T + (size_t)(rb + c)*128 + mt*16 + 4*q) = tv;
  }
}

// ---------------- Kernel 2: flash attention partials (EXACT R8 — proven) ---
// R8 proven best (55.1-55.6us): 64-key tiles, nt=2, grid 512, deferred
// l-sum, max3 tree, per-wave private Pbuf, 1 barrier/iter, full-iteration
// prefetch. UNTOUCHED this round (clean attribution for the mlpz change).
// Lessons ledger: (1) >=64-key tiles (R2); (2) occupancy-by-restructure is
// 0-for-4 (R1,R2,R3,R9); (3) ALL MFMA operands in lgkmcnt domain — global
// loads + DMA in one vmcnt FIFO across a conditional forces vmcnt(0) and
// drains prefetch (R1, R9: VGPR=84 proved compiler couldn't hold az);
// (4) T13 defer-max HURT (R4); (5) deferred l-sum WIN (R6: -2.8us);
// (6) v_pk_f32 on live accs -> spill cliff (R7); (7) P^T rows 128B,
// sw=(c&7)*8; (8) NEVER __launch_bounds__(256,3+); (9) barrier count is
// NOT the cost (R8 neutral).
__global__ __launch_bounds__(256,2) void flash_kernel(
    const half_t* __restrict__ T, const half_t* __restrict__ Zt,
    half_t* __restrict__ Pacc, float* __restrict__ Pm, float* __restrict__ Pl)
{
  __shared__ half_t Tbuf[2][16*512];    // 32 KB
  __shared__ half_t Zbuf[2][16*512];    // 32 KB
  __shared__ half_t Pbuf[4][32*64];     // 16 KB — per-wave private P^T
  const int tid = threadIdx.x;
  const int w = tid >> 6, lane = tid & 63;
  const int q = lane >> 4, c = lane & 15;
  const int bx = blockIdx.x;
  const int qb = bx >> 3, kh = bx & 7;
  const int wrow = qb*128 + w*32;
  const int sw = (c & 7) * 8;

  hx8 bq[2][4];
#pragma unroll
  for (int nt=0;nt<2;++nt)
#pragma unroll
    for (int ks=0;ks<4;++ks)
      bq[nt][ks] = *(const hx8*)(T + (size_t)(wrow + nt*16 + c)*128 + ks*32 + q*8);

  fx4 oacc[8][2];
#pragma unroll
  for (int mtd=0;mtd<8;++mtd)
#pragma unroll
    for (int nt=0;nt<2;++nt) oacc[mtd][nt] = (fx4){0.f,0.f,0.f,0.f};
  float m_run[2] = {-1e30f,-1e30f};
  float l_run[2] = {0.f,0.f};          // per-lane PARTIAL sums (reduced at end)

  const int kbase = kh*1024;
  half_t* Psw = &Pbuf[w][0];           // wave-private 32x64-half P^T

  auto issue_loads = [&](int kt0, int b) {
    if (w < 2) {
#pragma unroll
      for (int i=0;i<8;++i) {
        int f = w*8 + i, mt = f >> 2, ks = f & 3;
        const half_t* gp = T + (size_t)(kt0 + mt*16 + c)*128 + ks*32 + q*8;
        half_t* lp = &Tbuf[b][f*512 + lane*8];
        __builtin_amdgcn_global_load_lds(
            (const __attribute__((address_space(1))) void*)gp,
            (__attribute__((address_space(3))) void*)lp, 16, 0, 0);
      }
    } else {
#pragma unroll
      for (int i=0;i<8;++i) {
        int f2 = (w-2)*8 + i, mtd = f2 >> 1, ks2 = f2 & 1;
        const half_t* gp = Zt + (size_t)(mtd*16 + c)*8192 + kt0 + ks2*32 + q*8;
        half_t* lp = &Zbuf[b][f2*512 + lane*8];
        __builtin_amdgcn_global_load_lds(
            (const __attribute__((address_space(1))) void*)gp,
            (__attribute__((address_space(3))) void*)lp, 16, 0, 0);
      }
    }
  };

  issue_loads(kbase, 0);

  for (int t=0;t<16;++t) {
    const int cur = t & 1;
    __syncthreads();                    // THE barrier: drains own DMA (vmcnt)
                                        // + publishes both buffers of iter t
    half_t* Tcur = Tbuf[cur];
    half_t* Zcur = Zbuf[cur];

    // prefetch t+1 NOW: cur^1 is dead (barrier retired all t-1 reads)
    if (t < 15) issue_loads(kbase + (t+1)*64, cur ^ 1);

    // ---- scores ----
    fx4 sacc[4][2];
#pragma unroll
    for (int mt=0;mt<4;++mt)
#pragma unroll
      for (int nt=0;nt<2;++nt) sacc[mt][nt] = (fx4){0.f,0.f,0.f,0.f};
#pragma unroll
    for (int ks=0;ks<4;++ks)
#pragma unroll
      for (int mt=0;mt<4;++mt) {
        hx8 ak = *(const hx8*)(&Tcur[(mt*4+ks)*512 + lane*8]);
        sacc[mt][0] = __builtin_amdgcn_mfma_f32_16x16x32_f16(ak, bq[0][ks], sacc[mt][0], 0,0,0);
        sacc[mt][1] = __builtin_amdgcn_mfma_f32_16x16x32_f16(ak, bq[1][ks], sacc[mt][1], 0,0,0);
      }

    // ---- online softmax (per-lane partial l; only the MAX is shfl'd) ----
    hx4 pk[2][4];
#pragma unroll
    for (int nt=0;nt<2;++nt) {
      float a0 = fmaxf(fmaxf(sacc[0][nt][0], sacc[0][nt][1]), sacc[0][nt][2]);
      float a1 = fmaxf(fmaxf(sacc[0][nt][3], sacc[1][nt][0]), sacc[1][nt][1]);
      float a2 = fmaxf(fmaxf(sacc[1][nt][2], sacc[1][nt][3]), sacc[2][nt][0]);
      float a3 = fmaxf(fmaxf(sacc[2][nt][1], sacc[2][nt][2]), sacc[2][nt][3]);
      float a4 = fmaxf(fmaxf(sacc[3][nt][0], sacc[3][nt][1]), sacc[3][nt][2]);
      float mx = fmaxf(fmaxf(fmaxf(a0, a1), fmaxf(a2, a3)),
                       fmaxf(a4, sacc[3][nt][3]));
      mx = fmaxf(mx, __shfl_xor(mx, 16, 64));
      mx = fmaxf(mx, __shfl_xor(mx, 32, 64));
      float mnew = fmaxf(m_run[nt], mx);
      float alpha = __builtin_amdgcn_exp2f((m_run[nt]-mnew)*LOG2E);
      m_run[nt] = mnew;
      float nb = mnew*LOG2E;
      float rs = 0.f;
#pragma unroll
      for (int mt=0;mt<4;++mt) {
#pragma unroll
        for (int i=0;i<4;++i) {
          float p = __builtin_amdgcn_exp2f(sacc[mt][nt][i]*LOG2E - nb);
          rs += p;
          pk[nt][mt][i] = (half_t)p;
        }
      }
      l_run[nt] = l_run[nt]*alpha + rs;   // per-lane partial (no shfl here)
#pragma unroll
      for (int mtd=0;mtd<8;++mtd)
#pragma unroll
        for (int i=0;i<4;++i) oacc[mtd][nt][i] *= alpha;
    }

    // P^T into wave-private region (no inter-wave race -> NO barrier)
#pragma unroll
    for (int nt=0;nt<2;++nt)
#pragma unroll
      for (int mt=0;mt<4;++mt)
        *(hx4*)(&Psw[(nt*16 + c)*64 + ((mt*16 + 4*q) ^ sw)]) = pk[nt][mt];

    // ---- PV ----
#pragma unroll
    for (int ks2=0;ks2<2;++ks2) {
      hx8 bp0 = *(const hx8*)(&Psw[(c     )*64 + ((ks2*32 + q*8) ^ sw)]);
      hx8 bp1 = *(const hx8*)(&Psw[(16 + c)*64 + ((ks2*32 + q*8) ^ sw)]);
#pragma unroll
      for (int mtd=0;mtd<8;++mtd) {
        hx8 az = *(const hx8*)(&Zcur[(mtd*2+ks2)*512 + lane*8]);
        oacc[mtd][0] = __builtin_amdgcn_mfma_f32_16x16x32_f16(az, bp0, oacc[mtd][0], 0,0,0);
        oacc[mtd][1] = __builtin_amdgcn_mfma_f32_16x16x32_f16(az, bp1, oacc[mtd][1], 0,0,0);
      }
    }
  }

  // epilogue: reduce the deferred l partials across the 4 lanes per q-row
#pragma unroll
  for (int nt=0;nt<2;++nt) {
    float lf = l_run[nt];
    lf += __shfl_xor(lf, 16, 64);
    lf += __shfl_xor(lf, 32, 64);
    float inv = 1.0f / lf;
    const size_t rowg = (size_t)(bx*128 + w*32 + nt*16 + c);
#pragma unroll
    for (int mtd=0;mtd<8;++mtd) {
      hx4 ov;
#pragma unroll
      for (int i=0;i<4;++i) ov[i] = (half_t)(oacc[mtd][nt][i]*inv);
      *(hx4*)(Pacc + rowg*128 + mtd*16 + 4*q) = ov;
    }
    if (q == 0) {
      Pm[rowg] = m_run[nt];
      Pl[rowg] = lf;
    }
  }
}

// ---------------- Kernel 3: merge NSPLIT key-split partials ----------------
// (unchanged)
__global__ __launch_bounds__(256) void merge_kernel(
    const float* __restrict__ Z, const half_t* __restrict__ Pacc,
    const float* __restrict__ Pm, const float* __restrict__ Pl,
    float* __restrict__ out)
{
  const int th = blockIdx.x*256 + threadIdx.x;
  const int r = th >> 5, cg = th & 31;
  const int qb = r >> 7, rr = r & 127;
  float mk[NSPLIT], lk[NSPLIT];
  float M = -1e30f;
#pragma unroll
  for (int k=0;k<NSPLIT;++k) {
    int p = qb*NSPLIT + k;
    mk[k] = Pm[p*128 + rr];
    lk[k] = Pl[p*128 + rr];
    M = fmaxf(M, mk[k]);
  }
  float L = 0.f, wk[NSPLIT];
#pragma unroll
  for (int k=0;k<NSPLIT;++k) { wk[k] = lk[k]*__builtin_amdgcn_exp2f((mk[k]-M)*LOG2E); L += wk[k]; }
  float o0=0.f,o1=0.f,o2=0.f,o3=0.f;
#pragma unroll
  for (int k=0;k<NSPLIT;++k) {
    int p = qb*NSPLIT + k;
    hx4 v = *(const hx4*)(Pacc + ((size_t)p*128 + rr)*128 + cg*4);
    o0 += wk[k]*(float)v[0]; o1 += wk[k]*(float)v[1];
    o2 += wk[k]*(float)v[2]; o3 += wk[k]*(float)v[3];
  }
  float invL = 1.0f / L;
  fx4 zv = *(const fx4*)(Z + (size_t)r*128 + cg*4);
  fx4 res;
  res[0] = (1.f-TAU)*zv[0] + TAU*o0*invL;
  res[1] = (1.f-TAU)*zv[1] + TAU*o1*invL;
  res[2] = (1.f-TAU)*zv[2] + TAU*o2*invL;
  res[3] = (1.f-TAU)*zv[3] + TAU*o3*invL;
  *(fx4*)(out + (size_t)r*128 + cg*4) = res;
}

extern "C" void kernel_launch(void* const* d_in, const int* in_sizes, int n_in,
                              void* d_out, int out_size, void* d_ws, size_t ws_size,
                              hipStream_t stream) {
  const float* Z  = (const float*)d_in[0];
  const float* W1 = (const float*)d_in[1];
  const float* b1 = (const float*)d_in[2];
  const float* W2 = (const float*)d_in[3];
  const float* b2 = (const float*)d_in[4];
  float* out = (float*)d_out;

  char* ws = (char*)d_ws;
  const size_t NBLK = 64 * NSPLIT;                                // 512
  half_t* Thi  = (half_t*)(ws);                                   // 2 MB
  half_t* Zth  = (half_t*)(ws + (size_t)2*1024*1024);             // 2 MB
  half_t* Pacc = (half_t*)(ws + (size_t)4*1024*1024);             // 16 MB
  float*  Pm   = (float*)(ws + (size_t)4*1024*1024 + NBLK*128*128*2);
  float*  Pl   = Pm + NBLK*128;
  half_t* Wh1  = (half_t*)(ws + (size_t)20*1024*1024 + 512*1024); // 32 KB
  half_t* Wh2  = Wh1 + 32*64*8;                                   // 32 KB

  hipLaunchKernelGGL(wpack_kernel, dim3(16),   dim3(256), 0, stream, W1, W2, Wh1, Wh2);
  hipLaunchKernelGGL(mlpz_kernel,  dim3(1024), dim3(256), 0, stream, Z, Wh1, b1, Wh2, b2, Thi, Zth);
  hipLaunchKernelGGL(flash_kernel, dim3(NBLK), dim3(256), 0, stream, Thi, Zth, Pacc, Pm, Pl);
  hipLaunchKernelGGL(merge_kernel, dim3(1024), dim3(256), 0, stream, Z, Pacc, Pm, Pl, out);
}